// Round 17
// baseline (889.697 us; speedup 1.0000x reference)
//
#include <hip/hip_runtime.h>
#include <hip/hip_bf16.h>
#include <stdint.h>

#define T_TOK 4096
#define HID   2048
#define FFN_D 4096
#define NE    8
#define PADB  256     // expert padding granularity = BM of the 8-wave GEMM
#define PADMAX 10240  // max padded rows (8 experts x up to 1280)

typedef __attribute__((ext_vector_type(8))) short  short8;
typedef __attribute__((ext_vector_type(4))) float  f32x4;
typedef __attribute__((ext_vector_type(4))) unsigned short u16x4;
typedef unsigned short u16;

__device__ __forceinline__ u16 f2bf(float f) {
    unsigned u = __float_as_uint(f);
    u += 0x7FFFu + ((u >> 16) & 1u);   // RNE
    return (u16)(u >> 16);
}
__device__ __forceinline__ float bf2f(u16 v) {
    return __uint_as_float(((unsigned)v) << 16);
}

// direct global->LDS, 16B per lane; LDS dest = wave-uniform base + lane*16
#define GLD16(g, l) __builtin_amdgcn_global_load_lds( \
    (const __attribute__((address_space(1))) unsigned int*)(g), \
    (__attribute__((address_space(3))) unsigned int*)(l), 16, 0, 0)

// ---------------- fp32 -> bf16 converter (single tensor; fallback path) --------
__global__ void k_convert(const float* __restrict__ s, u16* __restrict__ d, long n8) {
    for (long i = (long)blockIdx.x * 256 + threadIdx.x; i < n8; i += (long)gridDim.x * 256) {
        f32x4 a = *((const f32x4*)s + i * 2);
        f32x4 b = *((const f32x4*)s + i * 2 + 1);
        short8 o;
#pragma unroll
        for (int q = 0; q < 4; ++q) { o[q] = (short)f2bf(a[q]); o[q + 4] = (short)f2bf(b[q]); }
        *(short8*)(d + i * 8) = o;
    }
}

// ---------------- fp32 -> bf16 converter, two tensors (fallback path) ----------
__global__ void k_convert2(const float* __restrict__ s0, u16* __restrict__ d0,
                           const float* __restrict__ s1, u16* __restrict__ d1, long n8) {
    for (long i = (long)blockIdx.x * 256 + threadIdx.x; i < 2 * n8; i += (long)gridDim.x * 256) {
        const float* s = (i < n8) ? s0 : s1;
        u16*         d = (i < n8) ? d0 : d1;
        long         j = (i < n8) ? i : (i - n8);
        f32x4 a = *((const f32x4*)s + j * 2);
        f32x4 b = *((const f32x4*)s + j * 2 + 1);
        short8 o;
#pragma unroll
        for (int q = 0; q < 4; ++q) { o[q] = (short)f2bf(a[q]); o[q + 4] = (short)f2bf(b[q]); }
        *(short8*)(d + j * 8) = o;
    }
}

// ---------------- router body (1 wave per token; emits xb bf16) ----------------
__device__ __forceinline__ void router_body(
    int blk, int tid,
    const float* __restrict__ x, const float* __restrict__ wr,
    u16* __restrict__ xb, int* __restrict__ topk_id,
    float* __restrict__ topk_w, int* __restrict__ counts) {
    int lane = tid & 63;
    int t = blk * 4 + (tid >> 6);
    const float* xr = x + (size_t)t * HID;
    u16* xbr = xb + (size_t)t * HID;
    float acc[8];
#pragma unroll
    for (int e = 0; e < 8; ++e) acc[e] = 0.f;
    for (int h = lane; h < HID; h += 64) {
        float xv = xr[h];
        xbr[h] = f2bf(xv);                         // fused x -> bf16
        f32x4 w0 = *(const f32x4*)(wr + h * 8);
        f32x4 w1 = *(const f32x4*)(wr + h * 8 + 4);
#pragma unroll
        for (int q = 0; q < 4; ++q) { acc[q] += xv * w0[q]; acc[4 + q] += xv * w1[q]; }
    }
#pragma unroll
    for (int e = 0; e < 8; ++e) {
        float v = acc[e];
#pragma unroll
        for (int s = 32; s > 0; s >>= 1) v += __shfl_xor(v, s);
        acc[e] = v;
    }
    if (lane == 0) {
        int i0 = 0; float l0 = acc[0];
#pragma unroll
        for (int e = 1; e < 8; ++e) if (acc[e] > l0) { l0 = acc[e]; i0 = e; }
        int i1 = -1; float l1 = -3.4e38f;
#pragma unroll
        for (int e = 0; e < 8; ++e) if (e != i0 && acc[e] > l1) { l1 = acc[e]; i1 = e; }
        float wA = 1.f / (1.f + expf(l1 - l0));   // top-2 softmax renorm, denom cancels
        topk_id[t * 2] = i0;  topk_id[t * 2 + 1] = i1;
        topk_w[t * 2] = wA;   topk_w[t * 2 + 1] = 1.f - wA;
        atomicAdd(&counts[i0], 1);
        atomicAdd(&counts[i1], 1);
    }
}

// ---------------- standalone router (fallback path) ----------------
__global__ void k_router(const float* __restrict__ x, const float* __restrict__ wr,
                         u16* __restrict__ xb, int* __restrict__ topk_id,
                         float* __restrict__ topk_w, int* __restrict__ counts) {
    router_body(blockIdx.x, threadIdx.x, x, wr, xb, topk_id, topk_w, counts);
}

// ------- fused pre-pass: blocks [0,1024) router; rest convert w1,w3 -> bf16 ----
__global__ void k_pre(const float* __restrict__ x, const float* __restrict__ wr,
                      u16* __restrict__ xb, int* __restrict__ topk_id,
                      float* __restrict__ topk_w, int* __restrict__ counts,
                      const float* __restrict__ w1, u16* __restrict__ w1b,
                      const float* __restrict__ w3, u16* __restrict__ w3b, long n8) {
    if (blockIdx.x < 1024) {
        router_body(blockIdx.x, threadIdx.x, x, wr, xb, topk_id, topk_w, counts);
        return;
    }
    const long nb = (long)(gridDim.x - 1024);
    for (long i = (long)(blockIdx.x - 1024) * 256 + threadIdx.x; i < 2 * n8; i += nb * 256) {
        const float* s = (i < n8) ? w1 : w3;
        u16*         d = (i < n8) ? w1b : w3b;
        long         j = (i < n8) ? i : (i - n8);
        f32x4 a = *((const f32x4*)s + j * 2);
        f32x4 b = *((const f32x4*)s + j * 2 + 1);
        short8 o;
#pragma unroll
        for (int q = 0; q < 4; ++q) { o[q] = (short)f2bf(a[q]); o[q + 4] = (short)f2bf(b[q]); }
        *(short8*)(d + j * 8) = o;
    }
}

// ---------------- padded scan + fill (pad to 256) ----------------
__global__ void k_scan(const int* __restrict__ counts, int* __restrict__ pad_off,
                       int* __restrict__ perm_tok) {
    __shared__ int sTot;
    if (threadIdx.x == 0) {
        int o = 0;
#pragma unroll
        for (int e = 0; e < 8; ++e) { pad_off[e] = o; o += ((counts[e] + PADB - 1) / PADB) * PADB; }
        pad_off[8] = o; sTot = o;
    }
    __syncthreads();
    int tot = sTot;
    for (int i = threadIdx.x; i < tot; i += 256) perm_tok[i] = 0;  // filler = token 0
}

// ---------------- scatter tokens into expert lists ----------------
__global__ void k_scatter(const int* __restrict__ topk_id, int* __restrict__ cursors,
                          const int* __restrict__ pad_off, int* __restrict__ perm_tok,
                          int* __restrict__ pos_of) {
    int t = blockIdx.x * 256 + threadIdx.x;
    if (t >= T_TOK) return;
#pragma unroll
    for (int k = 0; k < 2; ++k) {
        int e = topk_id[t * 2 + k];
        int p = pad_off[e] + atomicAdd(&cursors[e], 1);
        perm_tok[p] = t;
        pos_of[t * 2 + k] = p;
    }
}

// =========== 256-row 8-wave GEMM, m201-style per-phase double barriers =======
// BM=256, BK=64, 512 thr (waves 2M x 4N). R17: each of the 4 phases per K-tile
// is {frag ds_reads + 2x GLD16 -> sched_barrier -> s_barrier -> sched_barrier
// -> setprio(1) 16-MFMA setprio(0) -> s_barrier}. All waves' reads issue
// before any MFMA starts (early waves' MFMA overlaps late waves' read tails);
// reads of phase p+1 never contend with MFMAs of phase p (m201 mechanism,
// 45.7->62.1% MfmaUtil on identical geometry). vmcnt(0) once per tile before
// phase-3's closing barrier publishes the next buffer (loads >=1 phase old;
// weights L2/L3-resident). Swizzle/offsets/epilogue identical to R16.
template<int KTOT, int NTOT, int BNt, int KSPLIT, bool DUAL, bool GATHER, bool CONV>
__global__ __launch_bounds__(512, 2) void k_gemm8(
    const u16* __restrict__ A,
    const u16* __restrict__ B0all,
    const u16* __restrict__ B1all,
    u16* __restrict__ C,
    const int* __restrict__ perm_tok,
    const int* __restrict__ pad_off,
    const float* __restrict__ W2c,
    u16* __restrict__ W2d,
    int gemmBlk, int convBlk)
{
    constexpr int BMt   = 256;
    constexpr int WCW   = BNt / 4;           // wave col width
    constexpr int NI    = WCW / 16;
    constexpr int CPX   = (NTOT / BNt) / 8;
    constexpr int KPART = KTOT / KSPLIT;
    constexpr int NK    = KPART / 64;
    constexpr int ATILE = BMt * 64;
    constexpr int BTILE = BNt * 64;
    constexpr int SEGB  = DUAL ? 8 : (BNt == 256 ? 8 : 4);

    const int bid = blockIdx.x;
    const int tid = threadIdx.x;

    if (CONV && bid >= gemmBlk) {
        // ---- tail converter block: contiguous slice of w2 fp32 -> bf16 ----
        const long per = (long)NE * FFN_D * HID / 8 / convBlk;   // f32x8 groups
        const long i0 = (long)(bid - gemmBlk) * per;
        for (long i = i0 + tid; i < i0 + per; i += 512) {
            f32x4 a = *((const f32x4*)W2c + i * 2);
            f32x4 b = *((const f32x4*)W2c + i * 2 + 1);
            short8 o;
#pragma unroll
            for (int q = 0; q < 4; ++q) { o[q] = (short)f2bf(a[q]); o[q + 4] = (short)f2bf(b[q]); }
            *(short8*)(W2d + i * 8) = o;
        }
        return;
    }

    const int xcd = bid & 7;
    int idx = bid >> 3;
    const int kh  = idx & (KSPLIT - 1);      // K-part fastest: same (m,n) adjacent
    idx /= KSPLIT;
    const int m0  = (idx / CPX) * BMt;
    if (m0 >= pad_off[8]) return;
    const int n0  = (xcd * CPX + (idx % CPX)) * BNt;
    int e = 0;
    while (pad_off[e + 1] <= m0) ++e;

    __shared__ u16 As[2 * ATILE];
    __shared__ u16 Bs0[2 * BTILE];
    __shared__ u16 Bs1[DUAL ? 2 * BTILE : 8];
    __shared__ int tokS[GATHER ? BMt : 8];

    const int w = tid >> 6, l = tid & 63;
    if (GATHER) {
        for (int i = tid; i < BMt; i += 512) tokS[i] = perm_tok[m0 + i];
        __syncthreads();
    }

    const u16* B0 = B0all + (size_t)e * NTOT * KTOT;
    const u16* B1 = DUAL ? (B1all + (size_t)e * NTOT * KTOT) : B0all;
    const int k0e = kh * KPART;              // element offset of this K-part

    // ---- wave-owned stage unit ----
    const int nseg = (w < 4) ? 8 : SEGB;     // wave-uniform
    const u16* gsrc[8];
    u16* ldst[8];
    int tstep;
    {
        const int c = (l & 7) ^ (l >> 3);   // inverse-swizzled source chunk
#pragma unroll
        for (int j = 0; j < 8; ++j) {
            const int js = (j < nseg) ? j : (j - 4);   // dup (never issued)
            const int rl = js * 8 + (l >> 3);
            if (w < 4) {                                 // A rows w*64..+63
                const int rt = w * 64 + rl;
                const long grow = GATHER ? (long)tokS[rt] : (long)(m0 + rt);
                gsrc[j] = A + grow * KTOT + k0e + c * 8;
                ldst[j] = (u16*)As + (w * 64 + js * 8) * 64;
                tstep = ATILE;
            } else if (DUAL && w >= 6) {                 // B1 strip (DUAL)
                const int rt = (w - 6) * 64 + rl;
                gsrc[j] = B1 + (size_t)(n0 + rt) * KTOT + k0e + c * 8;
                ldst[j] = (u16*)Bs1 + (rt - rl + js * 8) * 64;
                tstep = BTILE;
            } else {                                     // B0 strip
                const int rt = DUAL ? ((w - 4) * 64 + rl)
                                    : (BNt == 256 ? ((w - 4) * 64 + rl)
                                                  : ((w - 4) * 32 + rl));
                gsrc[j] = B0 + (size_t)(n0 + rt) * KTOT + k0e + c * 8;
                ldst[j] = (u16*)Bs0 + (rt - rl + js * 8) * 64;
                tstep = BTILE;
            }
        }
    }

    const int wr = w >> 2, wc = w & 3;
    const int fr = l & 15, fk = l >> 4, x7 = l & 7;
    const int pc0 = ((fk ^ x7) << 3);
    const int pc1 = pc0 ^ 32;                 // (fk+4)^x7 chunk = pc0 XOR 4
    const int aB = (wr * 128 + fr) * 64;
    const int bB = (wc * WCW + fr) * 64;

    f32x4 acc0[8][NI], acc1[8][NI];
    const f32x4 fz = {0.f, 0.f, 0.f, 0.f};
#pragma unroll
    for (int mi = 0; mi < 8; ++mi)
#pragma unroll
        for (int ni = 0; ni < NI; ++ni) { acc0[mi][ni] = fz; if (DUAL) acc1[mi][ni] = fz; }

    // prologue: stage tile 0 into buffer 0, full drain (one-time)
#pragma unroll
    for (int j = 0; j < 8; ++j) if (j < nseg) GLD16(gsrc[j], ldst[j]);
    asm volatile("s_waitcnt vmcnt(0)" ::: "memory");
    __builtin_amdgcn_s_barrier();
    __builtin_amdgcn_sched_barrier(0);

#pragma unroll 1
    for (int t = 0; t < NK; ++t) {
        const int cb = t & 1, nb2 = cb ^ 1;
        const u16* aC  = (const u16*)As  + cb * ATILE;
        const u16* b0C = (const u16*)Bs0 + cb * BTILE;
        const u16* b1C = (const u16*)Bs1 + (DUAL ? cb * BTILE : 0);
        const long kE = (long)(t + 1) * 64;
        const bool hasNext = (t + 1 < NK);

        short8 af[4], b0f[NI], b1f[NI];

        // ======== phase 0: frags(mi0-3,kk0)+B(kk0); GLD j0-1; MFMA ========
#pragma unroll
        for (int mi = 0; mi < 4; ++mi) af[mi] = *(const short8*)(aC + aB + mi * 1024 + pc0);
#pragma unroll
        for (int ni = 0; ni < NI; ++ni) {
            b0f[ni] = *(const short8*)(b0C + bB + ni * 1024 + pc0);
            if (DUAL) b1f[ni] = *(const short8*)(b1C + bB + ni * 1024 + pc0);
        }
        if (hasNext) {
#pragma unroll
            for (int j = 0; j < 2; ++j) if (j < nseg) GLD16(gsrc[j] + kE, ldst[j] + nb2 * tstep);
        }
        __builtin_amdgcn_sched_barrier(0);
        __builtin_amdgcn_s_barrier();
        __builtin_amdgcn_sched_barrier(0);
        __builtin_amdgcn_s_setprio(1);
#pragma unroll
        for (int mi = 0; mi < 4; ++mi)
#pragma unroll
            for (int ni = 0; ni < NI; ++ni) {
                acc0[mi][ni] = __builtin_amdgcn_mfma_f32_16x16x32_bf16(af[mi], b0f[ni], acc0[mi][ni], 0, 0, 0);
                if (DUAL)
                    acc1[mi][ni] = __builtin_amdgcn_mfma_f32_16x16x32_bf16(af[mi], b1f[ni], acc1[mi][ni], 0, 0, 0);
            }
        __builtin_amdgcn_s_setprio(0);
        __builtin_amdgcn_s_barrier();

        // ======== phase 1: frags(mi4-7,kk0); GLD j2-3; MFMA ========
#pragma unroll
        for (int mi = 0; mi < 4; ++mi) af[mi] = *(const short8*)(aC + aB + (mi + 4) * 1024 + pc0);
        if (hasNext) {
#pragma unroll
            for (int j = 2; j < 4; ++j) if (j < nseg) GLD16(gsrc[j] + kE, ldst[j] + nb2 * tstep);
        }
        __builtin_amdgcn_sched_barrier(0);
        __builtin_amdgcn_s_barrier();
        __builtin_amdgcn_sched_barrier(0);
        __builtin_amdgcn_s_setprio(1);
#pragma unroll
        for (int mi = 0; mi < 4; ++mi)
#pragma unroll
            for (int ni = 0; ni < NI; ++ni) {
                acc0[mi + 4][ni] = __builtin_amdgcn_mfma_f32_16x16x32_bf16(af[mi], b0f[ni], acc0[mi + 4][ni], 0, 0, 0);
                if (DUAL)
                    acc1[mi + 4][ni] = __builtin_amdgcn_mfma_f32_16x16x32_bf16(af[mi], b1f[ni], acc1[mi + 4][ni], 0, 0, 0);
            }
        __builtin_amdgcn_s_setprio(0);
        __builtin_amdgcn_s_barrier();

        // ======== phase 2: frags(mi0-3,kk1)+B(kk1); GLD j4-5; MFMA ========
#pragma unroll
        for (int mi = 0; mi < 4; ++mi) af[mi] = *(const short8*)(aC + aB + mi * 1024 + pc1);
#pragma unroll
        for (int ni = 0; ni < NI; ++ni) {
            b0f[ni] = *(const short8*)(b0C + bB + ni * 1024 + pc1);
            if (DUAL) b1f[ni] = *(const short8*)(b1C + bB + ni * 1024 + pc1);
        }
        if (hasNext) {
#pragma unroll
            for (int j = 4; j < 6; ++j) if (j < nseg) GLD16(gsrc[j] + kE, ldst[j] + nb2 * tstep);
        }
        __builtin_amdgcn_sched_barrier(0);
        __builtin_amdgcn_s_barrier();
        __builtin_amdgcn_sched_barrier(0);
        __builtin_amdgcn_s_setprio(1);
#pragma unroll
        for (int mi = 0; mi < 4; ++mi)
#pragma unroll
            for (int ni = 0; ni < NI; ++ni) {
                acc0[mi][ni] = __builtin_amdgcn_mfma_f32_16x16x32_bf16(af[mi], b0f[ni], acc0[mi][ni], 0, 0, 0);
                if (DUAL)
                    acc1[mi][ni] = __builtin_amdgcn_mfma_f32_16x16x32_bf16(af[mi], b1f[ni], acc1[mi][ni], 0, 0, 0);
            }
        __builtin_amdgcn_s_setprio(0);
        __builtin_amdgcn_s_barrier();

        // ======== phase 3: frags(mi4-7,kk1); GLD j6-7; MFMA; publish ========
#pragma unroll
        for (int mi = 0; mi < 4; ++mi) af[mi] = *(const short8*)(aC + aB + (mi + 4) * 1024 + pc1);
        if (hasNext) {
#pragma unroll
            for (int j = 6; j < 8; ++j) if (j < nseg) GLD16(gsrc[j] + kE, ldst[j] + nb2 * tstep);
        }
        __builtin_amdgcn_sched_barrier(0);
        __builtin_amdgcn_s_barrier();
        __builtin_amdgcn_sched_barrier(0);
        __builtin_amdgcn_s_setprio(1);
#pragma unroll
        for (int mi = 0; mi < 4; ++mi)
#pragma unroll
            for (int ni = 0; ni < NI; ++ni) {
                acc0[mi + 4][ni] = __builtin_amdgcn_mfma_f32_16x16x32_bf16(af[mi], b0f[ni], acc0[mi + 4][ni], 0, 0, 0);
                if (DUAL)
                    acc1[mi + 4][ni] = __builtin_amdgcn_mfma_f32_16x16x32_bf16(af[mi], b1f[ni], acc1[mi + 4][ni], 0, 0, 0);
            }
        __builtin_amdgcn_s_setprio(0);
        // tile boundary: own stages (issued phases 0-3) landed; publish nb
        asm volatile("s_waitcnt vmcnt(0)" ::: "memory");
        __builtin_amdgcn_sched_barrier(0);
        __builtin_amdgcn_s_barrier();
        __builtin_amdgcn_sched_barrier(0);
    }

    // epilogue: C/D layout col=lane&15, row=(lane>>4)*4+reg; DUAL -> SwiGLU
    u16* Co = C + (KSPLIT > 1 ? (size_t)kh * PADMAX * NTOT : 0);
    const int er = (l >> 4) * 4;
    const int ec = l & 15;
#pragma unroll
    for (int mi = 0; mi < 8; ++mi)
#pragma unroll
        for (int ni = 0; ni < NI; ++ni)
#pragma unroll
            for (int r = 0; r < 4; ++r) {
                size_t prow = (size_t)(m0 + wr * 128 + mi * 16 + er + r);
                int col = n0 + wc * WCW + ni * 16 + ec;
                float v = acc0[mi][ni][r];
                float res;
                if (DUAL) {
                    float g3 = acc1[mi][ni][r];
                    res = v / (1.f + __expf(-v)) * g3;   // silu(g1)*g3
                } else {
                    res = v;
                }
                Co[prow * NTOT + col] = f2bf(res);
            }
}

// ---------------- weighted combine (sums 4 split-K bf16 partials) ----------------
__global__ void k_combine4(const u16* __restrict__ y, const int* __restrict__ pos_of,
                           const float* __restrict__ topk_w, float* __restrict__ out) {
    int idx = blockIdx.x * 256 + threadIdx.x;    // exactly T * (H/4)
    int t  = idx >> 9;
    int c4 = (idx & 511) << 2;
    int p0 = pos_of[t * 2], p1 = pos_of[t * 2 + 1];
    float w0 = topk_w[t * 2], w1 = topk_w[t * 2 + 1];
    const size_t PS = (size_t)PADMAX * HID;
    f32x4 o = {0.f, 0.f, 0.f, 0.f};
#pragma unroll
    for (int p = 0; p < 4; ++p) {
        u16x4 a = *(const u16x4*)(y + p * PS + (size_t)p0 * HID + c4);
        u16x4 b = *(const u16x4*)(y + p * PS + (size_t)p1 * HID + c4);
#pragma unroll
        for (int q = 0; q < 4; ++q) o[q] += w0 * bf2f(a[q]) + w1 * bf2f(b[q]);
    }
    *(f32x4*)(out + (size_t)t * HID + c4) = o;
    if (idx == 0) out[(size_t)T_TOK * HID] = 0.f;   // second output: zeros((1,))
}

// ---------------- weighted combine (2 partials; fallback path) ----------------
__global__ void k_combine2(const u16* __restrict__ y0, const u16* __restrict__ y1,
                           const int* __restrict__ pos_of,
                           const float* __restrict__ topk_w, float* __restrict__ out) {
    int idx = blockIdx.x * 256 + threadIdx.x;
    int t  = idx >> 9;
    int c4 = (idx & 511) << 2;
    int p0 = pos_of[t * 2], p1 = pos_of[t * 2 + 1];
    float w0 = topk_w[t * 2], w1 = topk_w[t * 2 + 1];
    u16x4 a0 = *(const u16x4*)(y0 + (size_t)p0 * HID + c4);
    u16x4 a1 = *(const u16x4*)(y1 + (size_t)p0 * HID + c4);
    u16x4 b0 = *(const u16x4*)(y0 + (size_t)p1 * HID + c4);
    u16x4 b1 = *(const u16x4*)(y1 + (size_t)p1 * HID + c4);
    f32x4 o;
#pragma unroll
    for (int q = 0; q < 4; ++q)
        o[q] = w0 * (bf2f(a0[q]) + bf2f(a1[q])) + w1 * (bf2f(b0[q]) + bf2f(b1[q]));
    *(f32x4*)(out + (size_t)t * HID + c4) = o;
    if (idx == 0) out[(size_t)T_TOK * HID] = 0.f;
}

__global__ void k_init(int* __restrict__ c) {
    if (threadIdx.x < 16) c[threadIdx.x] = 0;       // counts[8] + cursors[8]
}

extern "C" void kernel_launch(void* const* d_in, const int* in_sizes, int n_in,
                              void* d_out, int out_size, void* d_ws, size_t ws_size,
                              hipStream_t stream) {
    const float* x  = (const float*)d_in[0];
    const float* wr = (const float*)d_in[1];
    const float* w1 = (const float*)d_in[2];
    const float* w2 = (const float*)d_in[3];
    const float* w3 = (const float*)d_in[4];
    float* out = (float*)d_out;
    char* ws = (char*)d_ws;

    const long WN8 = (long)NE * FFN_D * HID / 8;     // per weight tensor, x8 groups
    const size_t NEED = 503459840ull;                // main layout incl. separate w2b

    if (ws_size >= NEED) {
        // ---- main path ----
        u16*  xb  = (u16*)(ws);                          // 16,777,216
        u16*  wA  = (u16*)(ws + 16777216);               // 134,217,728 (w1b)
        u16*  w3b = (u16*)(ws + 150994944);              // 134,217,728 (w3b)
        u16*  hb  = (u16*)(ws + 285212672);              // 83,886,080  (10240 x 4096 bf16)
        u16*  w2b = (u16*)(ws + 369098752);              // 134,217,728
        u16*  yb  = (u16*)(ws + 16777216);               // 4 x 41,943,040 partials (alias w1b+w3b)
        int*  perm_tok = (int*)(ws + 503316480);         // 10240 ints
        int*  pos_of   = (int*)(ws + 503357440);
        int*  topk_id  = (int*)(ws + 503390208);
        float* topk_w  = (float*)(ws + 503422976);
        int*  cnt      = (int*)(ws + 503455744);
        int*  counts   = cnt;
        int*  cursors  = cnt + 8;
        int*  pad_off  = cnt + 16;

        k_init<<<1, 64, 0, stream>>>(cnt);

        // fused: router (blocks 0-1023) + w1/w3 fp32->bf16 convert (blocks 1024+)
        k_pre<<<9216, 256, 0, stream>>>(x, wr, xb, topk_id, topk_w, counts,
                                        w1, wA, w3, w3b, WN8);
        k_scan<<<1, 256, 0, stream>>>(counts, pad_off, perm_tok);
        k_scatter<<<16, 256, 0, stream>>>(topk_id, cursors, pad_off, perm_tok, pos_of);

        // stage 1: h = silu(x@w1^T)*(x@w3^T), dual-B BN=128;
        // + 512 tail blocks convert w2 -> w2b (fills grid-tail idle CUs)
        k_gemm8<HID, FFN_D, 128, 1, true, true, true>
            <<<(FFN_D / 128) * 40 + 512, 512, 0, stream>>>(
            xb, wA, w3b, hb, perm_tok, pad_off, w2, w2b, (FFN_D / 128) * 40, 512);

        // stage 2: y = h @ w2b^T; single-B BN=256, split-K x4 (bf16 partials)
        k_gemm8<FFN_D, HID, 256, 4, false, false, false>
            <<<(HID / 256) * 40 * 4, 512, 0, stream>>>(
            hb, w2b, (const u16*)nullptr, yb, perm_tok, pad_off,
            (const float*)nullptr, (u16*)nullptr, 0, 0);

        k_combine4<<<8192, 256, 0, stream>>>(yb, pos_of, topk_w, out);
    } else {
        // ---- fallback: R10 sequence (~369.3 MB), split-K x2 ----
        u16*  xb  = (u16*)(ws);                          // 16,777,216
        u16*  wA  = (u16*)(ws + 16777216);               // 134,217,728 (w1b, later w2b)
        u16*  w3b = (u16*)(ws + 150994944);              // 134,217,728
        u16*  hb  = (u16*)(ws + 285212672);              // 83,886,080
        u16*  yb  = (u16*)(ws + 150994944);              // 2 partials alias w3b
        int*  perm_tok = (int*)(ws + 369098752);
        int*  pos_of   = (int*)(ws + 369139712);
        int*  topk_id  = (int*)(ws + 369172480);
        float* topk_w  = (float*)(ws + 369205248);
        int*  cnt      = (int*)(ws + 369238016);
        int*  counts   = cnt;
        int*  cursors  = cnt + 8;
        int*  pad_off  = cnt + 16;

        k_init<<<1, 64, 0, stream>>>(cnt);
        k_router<<<1024, 256, 0, stream>>>(x, wr, xb, topk_id, topk_w, counts);
        k_scan<<<1, 256, 0, stream>>>(counts, pad_off, perm_tok);
        k_scatter<<<16, 256, 0, stream>>>(topk_id, cursors, pad_off, perm_tok, pos_of);

        k_convert2<<<8192, 256, 0, stream>>>(w1, wA, w3, w3b, WN8);

        k_gemm8<HID, FFN_D, 128, 1, true, true, false>
            <<<(FFN_D / 128) * 40, 512, 0, stream>>>(
            xb, wA, w3b, hb, perm_tok, pad_off,
            (const float*)nullptr, (u16*)nullptr, 0, 0);

        k_convert<<<4096, 256, 0, stream>>>(w2, wA, WN8);  // reuse w1's slot

        k_gemm8<FFN_D, HID, 256, 2, false, false, false>
            <<<(HID / 256) * 40 * 2, 512, 0, stream>>>(
            hb, wA, (const u16*)nullptr, yb, perm_tok, pad_off,
            (const float*)nullptr, (u16*)nullptr, 0, 0);

        k_combine2<<<8192, 256, 0, stream>>>(yb, yb + (size_t)PADMAX * HID,
                                             pos_of, topk_w, out);
    }
}

// Round 18
// 826.034 us; speedup vs baseline: 1.0771x; 1.0771x over previous
//
#include <hip/hip_runtime.h>
#include <hip/hip_bf16.h>
#include <stdint.h>

#define T_TOK 4096
#define HID   2048
#define FFN_D 4096
#define NE    8
#define PADB  256     // expert padding granularity = BM of the 8-wave GEMM
#define PADMAX 10240  // max padded rows (8 experts x up to 1280)

typedef __attribute__((ext_vector_type(8))) short  short8;
typedef __attribute__((ext_vector_type(4))) float  f32x4;
typedef __attribute__((ext_vector_type(4))) unsigned short u16x4;
typedef unsigned short u16;

__device__ __forceinline__ u16 f2bf(float f) {
    unsigned u = __float_as_uint(f);
    u += 0x7FFFu + ((u >> 16) & 1u);   // RNE
    return (u16)(u >> 16);
}
__device__ __forceinline__ float bf2f(u16 v) {
    return __uint_as_float(((unsigned)v) << 16);
}

// direct global->LDS, 16B per lane; LDS dest = wave-uniform base + lane*16
#define GLD16(g, l) __builtin_amdgcn_global_load_lds( \
    (const __attribute__((address_space(1))) unsigned int*)(g), \
    (__attribute__((address_space(3))) unsigned int*)(l), 16, 0, 0)

// ---------------- fp32 -> bf16 converter (single tensor; fallback path) --------
__global__ void k_convert(const float* __restrict__ s, u16* __restrict__ d, long n8) {
    for (long i = (long)blockIdx.x * 256 + threadIdx.x; i < n8; i += (long)gridDim.x * 256) {
        f32x4 a = *((const f32x4*)s + i * 2);
        f32x4 b = *((const f32x4*)s + i * 2 + 1);
        short8 o;
#pragma unroll
        for (int q = 0; q < 4; ++q) { o[q] = (short)f2bf(a[q]); o[q + 4] = (short)f2bf(b[q]); }
        *(short8*)(d + i * 8) = o;
    }
}

// ---------------- fp32 -> bf16 converter, two tensors (fallback path) ----------
__global__ void k_convert2(const float* __restrict__ s0, u16* __restrict__ d0,
                           const float* __restrict__ s1, u16* __restrict__ d1, long n8) {
    for (long i = (long)blockIdx.x * 256 + threadIdx.x; i < 2 * n8; i += (long)gridDim.x * 256) {
        const float* s = (i < n8) ? s0 : s1;
        u16*         d = (i < n8) ? d0 : d1;
        long         j = (i < n8) ? i : (i - n8);
        f32x4 a = *((const f32x4*)s + j * 2);
        f32x4 b = *((const f32x4*)s + j * 2 + 1);
        short8 o;
#pragma unroll
        for (int q = 0; q < 4; ++q) { o[q] = (short)f2bf(a[q]); o[q + 4] = (short)f2bf(b[q]); }
        *(short8*)(d + j * 8) = o;
    }
}

// ---------------- router body (1 wave per token; emits xb bf16) ----------------
__device__ __forceinline__ void router_body(
    int blk, int tid,
    const float* __restrict__ x, const float* __restrict__ wr,
    u16* __restrict__ xb, int* __restrict__ topk_id,
    float* __restrict__ topk_w, int* __restrict__ counts) {
    int lane = tid & 63;
    int t = blk * 4 + (tid >> 6);
    const float* xr = x + (size_t)t * HID;
    u16* xbr = xb + (size_t)t * HID;
    float acc[8];
#pragma unroll
    for (int e = 0; e < 8; ++e) acc[e] = 0.f;
    for (int h = lane; h < HID; h += 64) {
        float xv = xr[h];
        xbr[h] = f2bf(xv);                         // fused x -> bf16
        f32x4 w0 = *(const f32x4*)(wr + h * 8);
        f32x4 w1 = *(const f32x4*)(wr + h * 8 + 4);
#pragma unroll
        for (int q = 0; q < 4; ++q) { acc[q] += xv * w0[q]; acc[4 + q] += xv * w1[q]; }
    }
#pragma unroll
    for (int e = 0; e < 8; ++e) {
        float v = acc[e];
#pragma unroll
        for (int s = 32; s > 0; s >>= 1) v += __shfl_xor(v, s);
        acc[e] = v;
    }
    if (lane == 0) {
        int i0 = 0; float l0 = acc[0];
#pragma unroll
        for (int e = 1; e < 8; ++e) if (acc[e] > l0) { l0 = acc[e]; i0 = e; }
        int i1 = -1; float l1 = -3.4e38f;
#pragma unroll
        for (int e = 0; e < 8; ++e) if (e != i0 && acc[e] > l1) { l1 = acc[e]; i1 = e; }
        float wA = 1.f / (1.f + expf(l1 - l0));   // top-2 softmax renorm, denom cancels
        topk_id[t * 2] = i0;  topk_id[t * 2 + 1] = i1;
        topk_w[t * 2] = wA;   topk_w[t * 2 + 1] = 1.f - wA;
        atomicAdd(&counts[i0], 1);
        atomicAdd(&counts[i1], 1);
    }
}

// ---------------- standalone router (fallback path) ----------------
__global__ void k_router(const float* __restrict__ x, const float* __restrict__ wr,
                         u16* __restrict__ xb, int* __restrict__ topk_id,
                         float* __restrict__ topk_w, int* __restrict__ counts) {
    router_body(blockIdx.x, threadIdx.x, x, wr, xb, topk_id, topk_w, counts);
}

// ------- fused pre-pass: blocks [0,1024) router; rest convert w1,w3 -> bf16 ----
__global__ void k_pre(const float* __restrict__ x, const float* __restrict__ wr,
                      u16* __restrict__ xb, int* __restrict__ topk_id,
                      float* __restrict__ topk_w, int* __restrict__ counts,
                      const float* __restrict__ w1, u16* __restrict__ w1b,
                      const float* __restrict__ w3, u16* __restrict__ w3b, long n8) {
    if (blockIdx.x < 1024) {
        router_body(blockIdx.x, threadIdx.x, x, wr, xb, topk_id, topk_w, counts);
        return;
    }
    const long nb = (long)(gridDim.x - 1024);
    for (long i = (long)(blockIdx.x - 1024) * 256 + threadIdx.x; i < 2 * n8; i += nb * 256) {
        const float* s = (i < n8) ? w1 : w3;
        u16*         d = (i < n8) ? w1b : w3b;
        long         j = (i < n8) ? i : (i - n8);
        f32x4 a = *((const f32x4*)s + j * 2);
        f32x4 b = *((const f32x4*)s + j * 2 + 1);
        short8 o;
#pragma unroll
        for (int q = 0; q < 4; ++q) { o[q] = (short)f2bf(a[q]); o[q + 4] = (short)f2bf(b[q]); }
        *(short8*)(d + j * 8) = o;
    }
}

// ---------------- padded scan + fill (pad to 256) ----------------
__global__ void k_scan(const int* __restrict__ counts, int* __restrict__ pad_off,
                       int* __restrict__ perm_tok) {
    __shared__ int sTot;
    if (threadIdx.x == 0) {
        int o = 0;
#pragma unroll
        for (int e = 0; e < 8; ++e) { pad_off[e] = o; o += ((counts[e] + PADB - 1) / PADB) * PADB; }
        pad_off[8] = o; sTot = o;
    }
    __syncthreads();
    int tot = sTot;
    for (int i = threadIdx.x; i < tot; i += 256) perm_tok[i] = 0;  // filler = token 0
}

// ---------------- scatter tokens into expert lists ----------------
__global__ void k_scatter(const int* __restrict__ topk_id, int* __restrict__ cursors,
                          const int* __restrict__ pad_off, int* __restrict__ perm_tok,
                          int* __restrict__ pos_of) {
    int t = blockIdx.x * 256 + threadIdx.x;
    if (t >= T_TOK) return;
#pragma unroll
    for (int k = 0; k < 2; ++k) {
        int e = topk_id[t * 2 + k];
        int p = pad_off[e] + atomicAdd(&cursors[e], 1);
        perm_tok[p] = t;
        pos_of[t * 2 + k] = p;
    }
}

// =========== 256-row 8-wave 4-phase GEMM, wave-owned stage units ============
// BM=256, BK=64, 512 thr (waves 2M x 4N). Templated BNt / KSPLIT / CONV.
// Schedule verified R6/R10/R11/R13/R16 (826 us pipeline, reproduced twice):
// loads for tile t+1 issue at phases 0-1 of tile t, one vmcnt(0)+barrier per
// K-tile. 3-bit row-XOR swizzle both sides (rule 21). Schedule variants
// tested and REJECTED: 3-buf counted vmcnt (R5, -8%), reg-frag dbuf (R12,
// null), kk-plane counted vmcnt (R14, -5%), m201 per-phase double barriers
// (R17, -8%) -> this structure is the empirical fixed point; do not touch.
template<int KTOT, int NTOT, int BNt, int KSPLIT, bool DUAL, bool GATHER, bool CONV>
__global__ __launch_bounds__(512, 2) void k_gemm8(
    const u16* __restrict__ A,
    const u16* __restrict__ B0all,
    const u16* __restrict__ B1all,
    u16* __restrict__ C,
    const int* __restrict__ perm_tok,
    const int* __restrict__ pad_off,
    const float* __restrict__ W2c,
    u16* __restrict__ W2d,
    int gemmBlk, int convBlk)
{
    constexpr int BMt   = 256;
    constexpr int WCW   = BNt / 4;           // wave col width
    constexpr int NI    = WCW / 16;
    constexpr int CPX   = (NTOT / BNt) / 8;
    constexpr int KPART = KTOT / KSPLIT;
    constexpr int NK    = KPART / 64;
    constexpr int ATILE = BMt * 64;
    constexpr int BTILE = BNt * 64;
    constexpr int SEGB  = DUAL ? 8 : (BNt == 256 ? 8 : 4);

    const int bid = blockIdx.x;
    const int tid = threadIdx.x;

    if (CONV && bid >= gemmBlk) {
        // ---- tail converter block: contiguous slice of w2 fp32 -> bf16 ----
        const long per = (long)NE * FFN_D * HID / 8 / convBlk;   // f32x8 groups
        const long i0 = (long)(bid - gemmBlk) * per;
        for (long i = i0 + tid; i < i0 + per; i += 512) {
            f32x4 a = *((const f32x4*)W2c + i * 2);
            f32x4 b = *((const f32x4*)W2c + i * 2 + 1);
            short8 o;
#pragma unroll
            for (int q = 0; q < 4; ++q) { o[q] = (short)f2bf(a[q]); o[q + 4] = (short)f2bf(b[q]); }
            *(short8*)(W2d + i * 8) = o;
        }
        return;
    }

    const int xcd = bid & 7;
    int idx = bid >> 3;
    const int kh  = idx & (KSPLIT - 1);      // K-part fastest: same (m,n) adjacent
    idx /= KSPLIT;
    const int m0  = (idx / CPX) * BMt;
    if (m0 >= pad_off[8]) return;
    const int n0  = (xcd * CPX + (idx % CPX)) * BNt;
    int e = 0;
    while (pad_off[e + 1] <= m0) ++e;

    __shared__ u16 As[2 * ATILE];
    __shared__ u16 Bs0[2 * BTILE];
    __shared__ u16 Bs1[DUAL ? 2 * BTILE : 8];
    __shared__ int tokS[GATHER ? BMt : 8];

    const int w = tid >> 6, l = tid & 63;
    if (GATHER) {
        for (int i = tid; i < BMt; i += 512) tokS[i] = perm_tok[m0 + i];
        __syncthreads();
    }

    const u16* B0 = B0all + (size_t)e * NTOT * KTOT;
    const u16* B1 = DUAL ? (B1all + (size_t)e * NTOT * KTOT) : B0all;
    const int k0e = kh * KPART;              // element offset of this K-part

    // ---- wave-owned stage unit ----
    const int nseg = (w < 4) ? 8 : SEGB;     // wave-uniform
    const u16* gsrc[8];
    u16* ldst[8];
    int tstep;
    {
        const int c = (l & 7) ^ (l >> 3);   // inverse-swizzled source chunk
#pragma unroll
        for (int j = 0; j < 8; ++j) {
            const int js = (j < nseg) ? j : (j - 4);   // dup (never issued)
            const int rl = js * 8 + (l >> 3);
            if (w < 4) {                                 // A rows w*64..+63
                const int rt = w * 64 + rl;
                const long grow = GATHER ? (long)tokS[rt] : (long)(m0 + rt);
                gsrc[j] = A + grow * KTOT + k0e + c * 8;
                ldst[j] = (u16*)As + (w * 64 + js * 8) * 64;
                tstep = ATILE;
            } else if (DUAL && w >= 6) {                 // B1 strip (DUAL)
                const int rt = (w - 6) * 64 + rl;
                gsrc[j] = B1 + (size_t)(n0 + rt) * KTOT + k0e + c * 8;
                ldst[j] = (u16*)Bs1 + (rt - rl + js * 8) * 64;
                tstep = BTILE;
            } else {                                     // B0 strip
                const int rt = DUAL ? ((w - 4) * 64 + rl)
                                    : (BNt == 256 ? ((w - 4) * 64 + rl)
                                                  : ((w - 4) * 32 + rl));
                gsrc[j] = B0 + (size_t)(n0 + rt) * KTOT + k0e + c * 8;
                ldst[j] = (u16*)Bs0 + (rt - rl + js * 8) * 64;
                tstep = BTILE;
            }
        }
    }

    const int wr = w >> 2, wc = w & 3;
    const int fr = l & 15, fk = l >> 4, x7 = l & 7;
    const int pc0 = ((fk ^ x7) << 3);
    const int pc1 = pc0 ^ 32;                 // (fk+4)^x7 chunk = pc0 XOR 4
    const int aB = (wr * 128 + fr) * 64;
    const int bB = (wc * WCW + fr) * 64;

    f32x4 acc0[8][NI], acc1[8][NI];
    const f32x4 fz = {0.f, 0.f, 0.f, 0.f};
#pragma unroll
    for (int mi = 0; mi < 8; ++mi)
#pragma unroll
        for (int ni = 0; ni < NI; ++ni) { acc0[mi][ni] = fz; if (DUAL) acc1[mi][ni] = fz; }

    // prologue: stage tile 0 into buffer 0, full drain (one-time)
#pragma unroll
    for (int j = 0; j < 8; ++j) if (j < nseg) GLD16(gsrc[j], ldst[j]);
    asm volatile("s_waitcnt vmcnt(0)" ::: "memory");
    __builtin_amdgcn_s_barrier();
    __builtin_amdgcn_sched_barrier(0);

#pragma unroll 1
    for (int t = 0; t < NK; ++t) {
        const int cb = t & 1, nb2 = cb ^ 1;
        const u16* aC  = (const u16*)As  + cb * ATILE;
        const u16* b0C = (const u16*)Bs0 + cb * BTILE;
        const u16* b1C = (const u16*)Bs1 + (DUAL ? cb * BTILE : 0);
        const long kE = (long)(t + 1) * 64;
        const bool hasNext = (t + 1 < NK);

        short8 af[4], b0f[NI], b1f[NI];

        // ---- P0: stage first half of next tile; mi0-3 x kk0 ----
        if (hasNext) {
#pragma unroll
            for (int j = 0; j < 4; ++j) if (j < nseg) GLD16(gsrc[j] + kE, ldst[j] + nb2 * tstep);
        }
#pragma unroll
        for (int mi = 0; mi < 4; ++mi) af[mi] = *(const short8*)(aC + aB + mi * 1024 + pc0);
#pragma unroll
        for (int ni = 0; ni < NI; ++ni) {
            b0f[ni] = *(const short8*)(b0C + bB + ni * 1024 + pc0);
            if (DUAL) b1f[ni] = *(const short8*)(b1C + bB + ni * 1024 + pc0);
        }
        __builtin_amdgcn_s_setprio(1);
#pragma unroll
        for (int mi = 0; mi < 4; ++mi)
#pragma unroll
            for (int ni = 0; ni < NI; ++ni) {
                acc0[mi][ni] = __builtin_amdgcn_mfma_f32_16x16x32_bf16(af[mi], b0f[ni], acc0[mi][ni], 0, 0, 0);
                if (DUAL)
                    acc1[mi][ni] = __builtin_amdgcn_mfma_f32_16x16x32_bf16(af[mi], b1f[ni], acc1[mi][ni], 0, 0, 0);
            }
        __builtin_amdgcn_s_setprio(0);

        // ---- P1: stage second half; mi4-7 x kk0 ----
        if (hasNext) {
#pragma unroll
            for (int j = 4; j < 8; ++j) if (j < nseg) GLD16(gsrc[j] + kE, ldst[j] + nb2 * tstep);
        }
#pragma unroll
        for (int mi = 0; mi < 4; ++mi) af[mi] = *(const short8*)(aC + aB + (mi + 4) * 1024 + pc0);
        __builtin_amdgcn_s_setprio(1);
#pragma unroll
        for (int mi = 0; mi < 4; ++mi)
#pragma unroll
            for (int ni = 0; ni < NI; ++ni) {
                acc0[mi + 4][ni] = __builtin_amdgcn_mfma_f32_16x16x32_bf16(af[mi], b0f[ni], acc0[mi + 4][ni], 0, 0, 0);
                if (DUAL)
                    acc1[mi + 4][ni] = __builtin_amdgcn_mfma_f32_16x16x32_bf16(af[mi], b1f[ni], acc1[mi + 4][ni], 0, 0, 0);
            }
        __builtin_amdgcn_s_setprio(0);

        // ---- P2: mi0-3 x kk1 ----
#pragma unroll
        for (int mi = 0; mi < 4; ++mi) af[mi] = *(const short8*)(aC + aB + mi * 1024 + pc1);
#pragma unroll
        for (int ni = 0; ni < NI; ++ni) {
            b0f[ni] = *(const short8*)(b0C + bB + ni * 1024 + pc1);
            if (DUAL) b1f[ni] = *(const short8*)(b1C + bB + ni * 1024 + pc1);
        }
        __builtin_amdgcn_s_setprio(1);
#pragma unroll
        for (int mi = 0; mi < 4; ++mi)
#pragma unroll
            for (int ni = 0; ni < NI; ++ni) {
                acc0[mi][ni] = __builtin_amdgcn_mfma_f32_16x16x32_bf16(af[mi], b0f[ni], acc0[mi][ni], 0, 0, 0);
                if (DUAL)
                    acc1[mi][ni] = __builtin_amdgcn_mfma_f32_16x16x32_bf16(af[mi], b1f[ni], acc1[mi][ni], 0, 0, 0);
            }
        __builtin_amdgcn_s_setprio(0);

        // ---- P3: mi4-7 x kk1 ----
#pragma unroll
        for (int mi = 0; mi < 4; ++mi) af[mi] = *(const short8*)(aC + aB + (mi + 4) * 1024 + pc1);
        __builtin_amdgcn_s_setprio(1);
#pragma unroll
        for (int mi = 0; mi < 4; ++mi)
#pragma unroll
            for (int ni = 0; ni < NI; ++ni) {
                acc0[mi + 4][ni] = __builtin_amdgcn_mfma_f32_16x16x32_bf16(af[mi], b0f[ni], acc0[mi + 4][ni], 0, 0, 0);
                if (DUAL)
                    acc1[mi + 4][ni] = __builtin_amdgcn_mfma_f32_16x16x32_bf16(af[mi], b1f[ni], acc1[mi + 4][ni], 0, 0, 0);
            }
        __builtin_amdgcn_s_setprio(0);

        // ---- tile boundary: own stages (issued at P0/P1) landed; publish ----
        asm volatile("s_waitcnt vmcnt(0)" ::: "memory");
        __builtin_amdgcn_s_barrier();
        __builtin_amdgcn_sched_barrier(0);
    }

    // epilogue: C/D layout col=lane&15, row=(lane>>4)*4+reg; DUAL -> SwiGLU
    u16* Co = C + (KSPLIT > 1 ? (size_t)kh * PADMAX * NTOT : 0);
    const int er = (l >> 4) * 4;
    const int ec = l & 15;
#pragma unroll
    for (int mi = 0; mi < 8; ++mi)
#pragma unroll
        for (int ni = 0; ni < NI; ++ni)
#pragma unroll
            for (int r = 0; r < 4; ++r) {
                size_t prow = (size_t)(m0 + wr * 128 + mi * 16 + er + r);
                int col = n0 + wc * WCW + ni * 16 + ec;
                float v = acc0[mi][ni][r];
                float res;
                if (DUAL) {
                    float g3 = acc1[mi][ni][r];
                    res = v / (1.f + __expf(-v)) * g3;   // silu(g1)*g3
                } else {
                    res = v;
                }
                Co[prow * NTOT + col] = f2bf(res);
            }
}

// ---------------- weighted combine (sums 4 split-K bf16 partials) ----------------
__global__ void k_combine4(const u16* __restrict__ y, const int* __restrict__ pos_of,
                           const float* __restrict__ topk_w, float* __restrict__ out) {
    int idx = blockIdx.x * 256 + threadIdx.x;    // exactly T * (H/4)
    int t  = idx >> 9;
    int c4 = (idx & 511) << 2;
    int p0 = pos_of[t * 2], p1 = pos_of[t * 2 + 1];
    float w0 = topk_w[t * 2], w1 = topk_w[t * 2 + 1];
    const size_t PS = (size_t)PADMAX * HID;
    f32x4 o = {0.f, 0.f, 0.f, 0.f};
#pragma unroll
    for (int p = 0; p < 4; ++p) {
        u16x4 a = *(const u16x4*)(y + p * PS + (size_t)p0 * HID + c4);
        u16x4 b = *(const u16x4*)(y + p * PS + (size_t)p1 * HID + c4);
#pragma unroll
        for (int q = 0; q < 4; ++q) o[q] += w0 * bf2f(a[q]) + w1 * bf2f(b[q]);
    }
    *(f32x4*)(out + (size_t)t * HID + c4) = o;
    if (idx == 0) out[(size_t)T_TOK * HID] = 0.f;   // second output: zeros((1,))
}

// ---------------- weighted combine (2 partials; fallback path) ----------------
__global__ void k_combine2(const u16* __restrict__ y0, const u16* __restrict__ y1,
                           const int* __restrict__ pos_of,
                           const float* __restrict__ topk_w, float* __restrict__ out) {
    int idx = blockIdx.x * 256 + threadIdx.x;
    int t  = idx >> 9;
    int c4 = (idx & 511) << 2;
    int p0 = pos_of[t * 2], p1 = pos_of[t * 2 + 1];
    float w0 = topk_w[t * 2], w1 = topk_w[t * 2 + 1];
    u16x4 a0 = *(const u16x4*)(y0 + (size_t)p0 * HID + c4);
    u16x4 a1 = *(const u16x4*)(y1 + (size_t)p0 * HID + c4);
    u16x4 b0 = *(const u16x4*)(y0 + (size_t)p1 * HID + c4);
    u16x4 b1 = *(const u16x4*)(y1 + (size_t)p1 * HID + c4);
    f32x4 o;
#pragma unroll
    for (int q = 0; q < 4; ++q)
        o[q] = w0 * (bf2f(a0[q]) + bf2f(a1[q])) + w1 * (bf2f(b0[q]) + bf2f(b1[q]));
    *(f32x4*)(out + (size_t)t * HID + c4) = o;
    if (idx == 0) out[(size_t)T_TOK * HID] = 0.f;
}

__global__ void k_init(int* __restrict__ c) {
    if (threadIdx.x < 16) c[threadIdx.x] = 0;       // counts[8] + cursors[8]
}

extern "C" void kernel_launch(void* const* d_in, const int* in_sizes, int n_in,
                              void* d_out, int out_size, void* d_ws, size_t ws_size,
                              hipStream_t stream) {
    const float* x  = (const float*)d_in[0];
    const float* wr = (const float*)d_in[1];
    const float* w1 = (const float*)d_in[2];
    const float* w2 = (const float*)d_in[3];
    const float* w3 = (const float*)d_in[4];
    float* out = (float*)d_out;
    char* ws = (char*)d_ws;

    const long WN8 = (long)NE * FFN_D * HID / 8;     // per weight tensor, x8 groups
    const size_t NEED = 503459840ull;                // main layout incl. separate w2b

    if (ws_size >= NEED) {
        // ---- main path ----
        u16*  xb  = (u16*)(ws);                          // 16,777,216
        u16*  wA  = (u16*)(ws + 16777216);               // 134,217,728 (w1b)
        u16*  w3b = (u16*)(ws + 150994944);              // 134,217,728 (w3b)
        u16*  hb  = (u16*)(ws + 285212672);              // 83,886,080  (10240 x 4096 bf16)
        u16*  w2b = (u16*)(ws + 369098752);              // 134,217,728
        u16*  yb  = (u16*)(ws + 16777216);               // 4 x 41,943,040 partials (alias w1b+w3b)
        int*  perm_tok = (int*)(ws + 503316480);         // 10240 ints
        int*  pos_of   = (int*)(ws + 503357440);
        int*  topk_id  = (int*)(ws + 503390208);
        float* topk_w  = (float*)(ws + 503422976);
        int*  cnt      = (int*)(ws + 503455744);
        int*  counts   = cnt;
        int*  cursors  = cnt + 8;
        int*  pad_off  = cnt + 16;

        k_init<<<1, 64, 0, stream>>>(cnt);

        // fused: router (blocks 0-1023) + w1/w3 fp32->bf16 convert (blocks 1024+)
        k_pre<<<9216, 256, 0, stream>>>(x, wr, xb, topk_id, topk_w, counts,
                                        w1, wA, w3, w3b, WN8);
        k_scan<<<1, 256, 0, stream>>>(counts, pad_off, perm_tok);
        k_scatter<<<16, 256, 0, stream>>>(topk_id, cursors, pad_off, perm_tok, pos_of);

        // stage 1: h = silu(x@w1^T)*(x@w3^T), dual-B BN=128;
        // + 512 tail blocks convert w2 -> w2b (fills grid-tail idle CUs)
        k_gemm8<HID, FFN_D, 128, 1, true, true, true>
            <<<(FFN_D / 128) * 40 + 512, 512, 0, stream>>>(
            xb, wA, w3b, hb, perm_tok, pad_off, w2, w2b, (FFN_D / 128) * 40, 512);

        // stage 2: y = h @ w2b^T; single-B BN=256, split-K x4 (bf16 partials
        // into the freed w1b/w3b region) -> ~37us blocks pack the grid tail
        k_gemm8<FFN_D, HID, 256, 4, false, false, false>
            <<<(HID / 256) * 40 * 4, 512, 0, stream>>>(
            hb, w2b, (const u16*)nullptr, yb, perm_tok, pad_off,
            (const float*)nullptr, (u16*)nullptr, 0, 0);

        k_combine4<<<8192, 256, 0, stream>>>(yb, pos_of, topk_w, out);
    } else {
        // ---- fallback: R10 sequence (~369.3 MB), split-K x2 ----
        u16*  xb  = (u16*)(ws);                          // 16,777,216
        u16*  wA  = (u16*)(ws + 16777216);               // 134,217,728 (w1b, later w2b)
        u16*  w3b = (u16*)(ws + 150994944);              // 134,217,728
        u16*  hb  = (u16*)(ws + 285212672);              // 83,886,080
        u16*  yb  = (u16*)(ws + 150994944);              // 2 partials alias w3b
        int*  perm_tok = (int*)(ws + 369098752);
        int*  pos_of   = (int*)(ws + 369139712);
        int*  topk_id  = (int*)(ws + 369172480);
        float* topk_w  = (float*)(ws + 369205248);
        int*  cnt      = (int*)(ws + 369238016);
        int*  counts   = cnt;
        int*  cursors  = cnt + 8;
        int*  pad_off  = cnt + 16;

        k_init<<<1, 64, 0, stream>>>(cnt);
        k_router<<<1024, 256, 0, stream>>>(x, wr, xb, topk_id, topk_w, counts);
        k_scan<<<1, 256, 0, stream>>>(counts, pad_off, perm_tok);
        k_scatter<<<16, 256, 0, stream>>>(topk_id, cursors, pad_off, perm_tok, pos_of);

        k_convert2<<<8192, 256, 0, stream>>>(w1, wA, w3, w3b, WN8);

        k_gemm8<HID, FFN_D, 128, 1, true, true, false>
            <<<(FFN_D / 128) * 40, 512, 0, stream>>>(
            xb, wA, w3b, hb, perm_tok, pad_off,
            (const float*)nullptr, (u16*)nullptr, 0, 0);

        k_convert<<<4096, 256, 0, stream>>>(w2, wA, WN8);  // reuse w1's slot

        k_gemm8<FFN_D, HID, 256, 2, false, false, false>
            <<<(HID / 256) * 40 * 2, 512, 0, stream>>>(
            hb, wA, (const u16*)nullptr, yb, perm_tok, pad_off,
            (const float*)nullptr, (u16*)nullptr, 0, 0);

        k_combine2<<<8192, 256, 0, stream>>>(yb, yb + (size_t)PADMAX * HID,
                                             pos_of, topk_w, out);
    }
}

// Round 19
// 825.861 us; speedup vs baseline: 1.0773x; 1.0002x over previous
//
#include <hip/hip_runtime.h>
#include <hip/hip_bf16.h>
#include <stdint.h>

#define T_TOK 4096
#define HID   2048
#define FFN_D 4096
#define NE    8
#define PADB  256     // expert padding granularity = BM of the 8-wave GEMM
#define PADMAX 10240  // max padded rows (8 experts x up to 1280)

typedef __attribute__((ext_vector_type(8))) short  short8;
typedef __attribute__((ext_vector_type(4))) float  f32x4;
typedef __attribute__((ext_vector_type(4))) unsigned short u16x4;
typedef unsigned short u16;

__device__ __forceinline__ u16 f2bf(float f) {
    unsigned u = __float_as_uint(f);
    u += 0x7FFFu + ((u >> 16) & 1u);   // RNE
    return (u16)(u >> 16);
}
__device__ __forceinline__ float bf2f(u16 v) {
    return __uint_as_float(((unsigned)v) << 16);
}

// direct global->LDS, 16B per lane; LDS dest = wave-uniform base + lane*16
#define GLD16(g, l) __builtin_amdgcn_global_load_lds( \
    (const __attribute__((address_space(1))) unsigned int*)(g), \
    (__attribute__((address_space(3))) unsigned int*)(l), 16, 0, 0)

// ---------------- fp32 -> bf16 converter (single tensor; fallback path) --------
__global__ void k_convert(const float* __restrict__ s, u16* __restrict__ d, long n8) {
    for (long i = (long)blockIdx.x * 256 + threadIdx.x; i < n8; i += (long)gridDim.x * 256) {
        f32x4 a = *((const f32x4*)s + i * 2);
        f32x4 b = *((const f32x4*)s + i * 2 + 1);
        short8 o;
#pragma unroll
        for (int q = 0; q < 4; ++q) { o[q] = (short)f2bf(a[q]); o[q + 4] = (short)f2bf(b[q]); }
        *(short8*)(d + i * 8) = o;
    }
}

// ---------------- fp32 -> bf16 converter, two tensors (fallback path) ----------
__global__ void k_convert2(const float* __restrict__ s0, u16* __restrict__ d0,
                           const float* __restrict__ s1, u16* __restrict__ d1, long n8) {
    for (long i = (long)blockIdx.x * 256 + threadIdx.x; i < 2 * n8; i += (long)gridDim.x * 256) {
        const float* s = (i < n8) ? s0 : s1;
        u16*         d = (i < n8) ? d0 : d1;
        long         j = (i < n8) ? i : (i - n8);
        f32x4 a = *((const f32x4*)s + j * 2);
        f32x4 b = *((const f32x4*)s + j * 2 + 1);
        short8 o;
#pragma unroll
        for (int q = 0; q < 4; ++q) { o[q] = (short)f2bf(a[q]); o[q + 4] = (short)f2bf(b[q]); }
        *(short8*)(d + j * 8) = o;
    }
}

// ---------------- router body (1 wave per token; emits xb bf16) ----------------
__device__ __forceinline__ void router_body(
    int blk, int tid,
    const float* __restrict__ x, const float* __restrict__ wr,
    u16* __restrict__ xb, int* __restrict__ topk_id,
    float* __restrict__ topk_w, int* __restrict__ counts) {
    int lane = tid & 63;
    int t = blk * 4 + (tid >> 6);
    const float* xr = x + (size_t)t * HID;
    u16* xbr = xb + (size_t)t * HID;
    float acc[8];
#pragma unroll
    for (int e = 0; e < 8; ++e) acc[e] = 0.f;
    for (int h = lane; h < HID; h += 64) {
        float xv = xr[h];
        xbr[h] = f2bf(xv);                         // fused x -> bf16
        f32x4 w0 = *(const f32x4*)(wr + h * 8);
        f32x4 w1 = *(const f32x4*)(wr + h * 8 + 4);
#pragma unroll
        for (int q = 0; q < 4; ++q) { acc[q] += xv * w0[q]; acc[4 + q] += xv * w1[q]; }
    }
#pragma unroll
    for (int e = 0; e < 8; ++e) {
        float v = acc[e];
#pragma unroll
        for (int s = 32; s > 0; s >>= 1) v += __shfl_xor(v, s);
        acc[e] = v;
    }
    if (lane == 0) {
        int i0 = 0; float l0 = acc[0];
#pragma unroll
        for (int e = 1; e < 8; ++e) if (acc[e] > l0) { l0 = acc[e]; i0 = e; }
        int i1 = -1; float l1 = -3.4e38f;
#pragma unroll
        for (int e = 0; e < 8; ++e) if (e != i0 && acc[e] > l1) { l1 = acc[e]; i1 = e; }
        float wA = 1.f / (1.f + expf(l1 - l0));   // top-2 softmax renorm, denom cancels
        topk_id[t * 2] = i0;  topk_id[t * 2 + 1] = i1;
        topk_w[t * 2] = wA;   topk_w[t * 2 + 1] = 1.f - wA;
        atomicAdd(&counts[i0], 1);
        atomicAdd(&counts[i1], 1);
    }
}

// ---------------- standalone router (fallback path) ----------------
__global__ void k_router(const float* __restrict__ x, const float* __restrict__ wr,
                         u16* __restrict__ xb, int* __restrict__ topk_id,
                         float* __restrict__ topk_w, int* __restrict__ counts) {
    router_body(blockIdx.x, threadIdx.x, x, wr, xb, topk_id, topk_w, counts);
}

// ------- fused pre-pass: blocks [0,1024) router; rest convert w1,w3 -> bf16 ----
__global__ void k_pre(const float* __restrict__ x, const float* __restrict__ wr,
                      u16* __restrict__ xb, int* __restrict__ topk_id,
                      float* __restrict__ topk_w, int* __restrict__ counts,
                      const float* __restrict__ w1, u16* __restrict__ w1b,
                      const float* __restrict__ w3, u16* __restrict__ w3b, long n8) {
    if (blockIdx.x < 1024) {
        router_body(blockIdx.x, threadIdx.x, x, wr, xb, topk_id, topk_w, counts);
        return;
    }
    const long nb = (long)(gridDim.x - 1024);
    for (long i = (long)(blockIdx.x - 1024) * 256 + threadIdx.x; i < 2 * n8; i += nb * 256) {
        const float* s = (i < n8) ? w1 : w3;
        u16*         d = (i < n8) ? w1b : w3b;
        long         j = (i < n8) ? i : (i - n8);
        f32x4 a = *((const f32x4*)s + j * 2);
        f32x4 b = *((const f32x4*)s + j * 2 + 1);
        short8 o;
#pragma unroll
        for (int q = 0; q < 4; ++q) { o[q] = (short)f2bf(a[q]); o[q + 4] = (short)f2bf(b[q]); }
        *(short8*)(d + j * 8) = o;
    }
}

// ---------------- padded scan + fill (pad to 256) ----------------
__global__ void k_scan(const int* __restrict__ counts, int* __restrict__ pad_off,
                       int* __restrict__ perm_tok) {
    __shared__ int sTot;
    if (threadIdx.x == 0) {
        int o = 0;
#pragma unroll
        for (int e = 0; e < 8; ++e) { pad_off[e] = o; o += ((counts[e] + PADB - 1) / PADB) * PADB; }
        pad_off[8] = o; sTot = o;
    }
    __syncthreads();
    int tot = sTot;
    for (int i = threadIdx.x; i < tot; i += 256) perm_tok[i] = 0;  // filler = token 0
}

// ---------------- scatter tokens into expert lists ----------------
__global__ void k_scatter(const int* __restrict__ topk_id, int* __restrict__ cursors,
                          const int* __restrict__ pad_off, int* __restrict__ perm_tok,
                          int* __restrict__ pos_of) {
    int t = blockIdx.x * 256 + threadIdx.x;
    if (t >= T_TOK) return;
#pragma unroll
    for (int k = 0; k < 2; ++k) {
        int e = topk_id[t * 2 + k];
        int p = pad_off[e] + atomicAdd(&cursors[e], 1);
        perm_tok[p] = t;
        pos_of[t * 2 + k] = p;
    }
}

// =========== 256-row 8-wave 4-phase GEMM, wave-owned stage units ============
// BM=256, BK=64, 512 thr (waves 2M x 4N). Templated BNt / KSPLIT / CONV.
// Schedule verified R6/R10/R11/R13/R16 (826 us pipeline, reproduced twice):
// loads for tile t+1 issue at phases 0-1 of tile t, one vmcnt(0)+barrier per
// K-tile. 3-bit row-XOR swizzle both sides (rule 21). Schedule variants
// tested and REJECTED: 3-buf counted vmcnt (R5, -8%), reg-frag dbuf (R12,
// null), kk-plane counted vmcnt (R14, -5%), m201 per-phase double barriers
// (R17, -8%) -> this structure is the empirical fixed point; do not touch.
template<int KTOT, int NTOT, int BNt, int KSPLIT, bool DUAL, bool GATHER, bool CONV>
__global__ __launch_bounds__(512, 2) void k_gemm8(
    const u16* __restrict__ A,
    const u16* __restrict__ B0all,
    const u16* __restrict__ B1all,
    u16* __restrict__ C,
    const int* __restrict__ perm_tok,
    const int* __restrict__ pad_off,
    const float* __restrict__ W2c,
    u16* __restrict__ W2d,
    int gemmBlk, int convBlk)
{
    constexpr int BMt   = 256;
    constexpr int WCW   = BNt / 4;           // wave col width
    constexpr int NI    = WCW / 16;
    constexpr int CPX   = (NTOT / BNt) / 8;
    constexpr int KPART = KTOT / KSPLIT;
    constexpr int NK    = KPART / 64;
    constexpr int ATILE = BMt * 64;
    constexpr int BTILE = BNt * 64;
    constexpr int SEGB  = DUAL ? 8 : (BNt == 256 ? 8 : 4);

    const int bid = blockIdx.x;
    const int tid = threadIdx.x;

    if (CONV && bid >= gemmBlk) {
        // ---- tail converter block: contiguous slice of w2 fp32 -> bf16 ----
        const long per = (long)NE * FFN_D * HID / 8 / convBlk;   // f32x8 groups
        const long i0 = (long)(bid - gemmBlk) * per;
        for (long i = i0 + tid; i < i0 + per; i += 512) {
            f32x4 a = *((const f32x4*)W2c + i * 2);
            f32x4 b = *((const f32x4*)W2c + i * 2 + 1);
            short8 o;
#pragma unroll
            for (int q = 0; q < 4; ++q) { o[q] = (short)f2bf(a[q]); o[q + 4] = (short)f2bf(b[q]); }
            *(short8*)(W2d + i * 8) = o;
        }
        return;
    }

    const int xcd = bid & 7;
    int idx = bid >> 3;
    const int kh  = idx & (KSPLIT - 1);      // K-part fastest: same (m,n) adjacent
    idx /= KSPLIT;
    const int m0  = (idx / CPX) * BMt;
    if (m0 >= pad_off[8]) return;
    const int n0  = (xcd * CPX + (idx % CPX)) * BNt;
    int e = 0;
    while (pad_off[e + 1] <= m0) ++e;

    __shared__ u16 As[2 * ATILE];
    __shared__ u16 Bs0[2 * BTILE];
    __shared__ u16 Bs1[DUAL ? 2 * BTILE : 8];
    __shared__ int tokS[GATHER ? BMt : 8];

    const int w = tid >> 6, l = tid & 63;
    if (GATHER) {
        for (int i = tid; i < BMt; i += 512) tokS[i] = perm_tok[m0 + i];
        __syncthreads();
    }

    const u16* B0 = B0all + (size_t)e * NTOT * KTOT;
    const u16* B1 = DUAL ? (B1all + (size_t)e * NTOT * KTOT) : B0all;
    const int k0e = kh * KPART;              // element offset of this K-part

    // ---- wave-owned stage unit ----
    const int nseg = (w < 4) ? 8 : SEGB;     // wave-uniform
    const u16* gsrc[8];
    u16* ldst[8];
    int tstep;
    {
        const int c = (l & 7) ^ (l >> 3);   // inverse-swizzled source chunk
#pragma unroll
        for (int j = 0; j < 8; ++j) {
            const int js = (j < nseg) ? j : (j - 4);   // dup (never issued)
            const int rl = js * 8 + (l >> 3);
            if (w < 4) {                                 // A rows w*64..+63
                const int rt = w * 64 + rl;
                const long grow = GATHER ? (long)tokS[rt] : (long)(m0 + rt);
                gsrc[j] = A + grow * KTOT + k0e + c * 8;
                ldst[j] = (u16*)As + (w * 64 + js * 8) * 64;
                tstep = ATILE;
            } else if (DUAL && w >= 6) {                 // B1 strip (DUAL)
                const int rt = (w - 6) * 64 + rl;
                gsrc[j] = B1 + (size_t)(n0 + rt) * KTOT + k0e + c * 8;
                ldst[j] = (u16*)Bs1 + (rt - rl + js * 8) * 64;
                tstep = BTILE;
            } else {                                     // B0 strip
                const int rt = DUAL ? ((w - 4) * 64 + rl)
                                    : (BNt == 256 ? ((w - 4) * 64 + rl)
                                                  : ((w - 4) * 32 + rl));
                gsrc[j] = B0 + (size_t)(n0 + rt) * KTOT + k0e + c * 8;
                ldst[j] = (u16*)Bs0 + (rt - rl + js * 8) * 64;
                tstep = BTILE;
            }
        }
    }

    const int wr = w >> 2, wc = w & 3;
    const int fr = l & 15, fk = l >> 4, x7 = l & 7;
    const int pc0 = ((fk ^ x7) << 3);
    const int pc1 = pc0 ^ 32;                 // (fk+4)^x7 chunk = pc0 XOR 4
    const int aB = (wr * 128 + fr) * 64;
    const int bB = (wc * WCW + fr) * 64;

    f32x4 acc0[8][NI], acc1[8][NI];
    const f32x4 fz = {0.f, 0.f, 0.f, 0.f};
#pragma unroll
    for (int mi = 0; mi < 8; ++mi)
#pragma unroll
        for (int ni = 0; ni < NI; ++ni) { acc0[mi][ni] = fz; if (DUAL) acc1[mi][ni] = fz; }

    // prologue: stage tile 0 into buffer 0, full drain (one-time)
#pragma unroll
    for (int j = 0; j < 8; ++j) if (j < nseg) GLD16(gsrc[j], ldst[j]);
    asm volatile("s_waitcnt vmcnt(0)" ::: "memory");
    __builtin_amdgcn_s_barrier();
    __builtin_amdgcn_sched_barrier(0);

#pragma unroll 1
    for (int t = 0; t < NK; ++t) {
        const int cb = t & 1, nb2 = cb ^ 1;
        const u16* aC  = (const u16*)As  + cb * ATILE;
        const u16* b0C = (const u16*)Bs0 + cb * BTILE;
        const u16* b1C = (const u16*)Bs1 + (DUAL ? cb * BTILE : 0);
        const long kE = (long)(t + 1) * 64;
        const bool hasNext = (t + 1 < NK);

        short8 af[4], b0f[NI], b1f[NI];

        // ---- P0: stage first half of next tile; mi0-3 x kk0 ----
        if (hasNext) {
#pragma unroll
            for (int j = 0; j < 4; ++j) if (j < nseg) GLD16(gsrc[j] + kE, ldst[j] + nb2 * tstep);
        }
#pragma unroll
        for (int mi = 0; mi < 4; ++mi) af[mi] = *(const short8*)(aC + aB + mi * 1024 + pc0);
#pragma unroll
        for (int ni = 0; ni < NI; ++ni) {
            b0f[ni] = *(const short8*)(b0C + bB + ni * 1024 + pc0);
            if (DUAL) b1f[ni] = *(const short8*)(b1C + bB + ni * 1024 + pc0);
        }
        __builtin_amdgcn_s_setprio(1);
#pragma unroll
        for (int mi = 0; mi < 4; ++mi)
#pragma unroll
            for (int ni = 0; ni < NI; ++ni) {
                acc0[mi][ni] = __builtin_amdgcn_mfma_f32_16x16x32_bf16(af[mi], b0f[ni], acc0[mi][ni], 0, 0, 0);
                if (DUAL)
                    acc1[mi][ni] = __builtin_amdgcn_mfma_f32_16x16x32_bf16(af[mi], b1f[ni], acc1[mi][ni], 0, 0, 0);
            }
        __builtin_amdgcn_s_setprio(0);

        // ---- P1: stage second half; mi4-7 x kk0 ----
        if (hasNext) {
#pragma unroll
            for (int j = 4; j < 8; ++j) if (j < nseg) GLD16(gsrc[j] + kE, ldst[j] + nb2 * tstep);
        }
#pragma unroll
        for (int mi = 0; mi < 4; ++mi) af[mi] = *(const short8*)(aC + aB + (mi + 4) * 1024 + pc0);
        __builtin_amdgcn_s_setprio(1);
#pragma unroll
        for (int mi = 0; mi < 4; ++mi)
#pragma unroll
            for (int ni = 0; ni < NI; ++ni) {
                acc0[mi + 4][ni] = __builtin_amdgcn_mfma_f32_16x16x32_bf16(af[mi], b0f[ni], acc0[mi + 4][ni], 0, 0, 0);
                if (DUAL)
                    acc1[mi + 4][ni] = __builtin_amdgcn_mfma_f32_16x16x32_bf16(af[mi], b1f[ni], acc1[mi + 4][ni], 0, 0, 0);
            }
        __builtin_amdgcn_s_setprio(0);

        // ---- P2: mi0-3 x kk1 ----
#pragma unroll
        for (int mi = 0; mi < 4; ++mi) af[mi] = *(const short8*)(aC + aB + mi * 1024 + pc1);
#pragma unroll
        for (int ni = 0; ni < NI; ++ni) {
            b0f[ni] = *(const short8*)(b0C + bB + ni * 1024 + pc1);
            if (DUAL) b1f[ni] = *(const short8*)(b1C + bB + ni * 1024 + pc1);
        }
        __builtin_amdgcn_s_setprio(1);
#pragma unroll
        for (int mi = 0; mi < 4; ++mi)
#pragma unroll
            for (int ni = 0; ni < NI; ++ni) {
                acc0[mi][ni] = __builtin_amdgcn_mfma_f32_16x16x32_bf16(af[mi], b0f[ni], acc0[mi][ni], 0, 0, 0);
                if (DUAL)
                    acc1[mi][ni] = __builtin_amdgcn_mfma_f32_16x16x32_bf16(af[mi], b1f[ni], acc1[mi][ni], 0, 0, 0);
            }
        __builtin_amdgcn_s_setprio(0);

        // ---- P3: mi4-7 x kk1 ----
#pragma unroll
        for (int mi = 0; mi < 4; ++mi) af[mi] = *(const short8*)(aC + aB + (mi + 4) * 1024 + pc1);
        __builtin_amdgcn_s_setprio(1);
#pragma unroll
        for (int mi = 0; mi < 4; ++mi)
#pragma unroll
            for (int ni = 0; ni < NI; ++ni) {
                acc0[mi + 4][ni] = __builtin_amdgcn_mfma_f32_16x16x32_bf16(af[mi], b0f[ni], acc0[mi + 4][ni], 0, 0, 0);
                if (DUAL)
                    acc1[mi + 4][ni] = __builtin_amdgcn_mfma_f32_16x16x32_bf16(af[mi], b1f[ni], acc1[mi + 4][ni], 0, 0, 0);
            }
        __builtin_amdgcn_s_setprio(0);

        // ---- tile boundary: own stages (issued at P0/P1) landed; publish ----
        asm volatile("s_waitcnt vmcnt(0)" ::: "memory");
        __builtin_amdgcn_s_barrier();
        __builtin_amdgcn_sched_barrier(0);
    }

    // epilogue: C/D layout col=lane&15, row=(lane>>4)*4+reg; DUAL -> SwiGLU
    u16* Co = C + (KSPLIT > 1 ? (size_t)kh * PADMAX * NTOT : 0);
    const int er = (l >> 4) * 4;
    const int ec = l & 15;
#pragma unroll
    for (int mi = 0; mi < 8; ++mi)
#pragma unroll
        for (int ni = 0; ni < NI; ++ni)
#pragma unroll
            for (int r = 0; r < 4; ++r) {
                size_t prow = (size_t)(m0 + wr * 128 + mi * 16 + er + r);
                int col = n0 + wc * WCW + ni * 16 + ec;
                float v = acc0[mi][ni][r];
                float res;
                if (DUAL) {
                    float g3 = acc1[mi][ni][r];
                    res = v / (1.f + __expf(-v)) * g3;   // silu(g1)*g3
                } else {
                    res = v;
                }
                Co[prow * NTOT + col] = f2bf(res);
            }
}

// ---------------- weighted combine (sums 4 split-K bf16 partials) ----------------
__global__ void k_combine4(const u16* __restrict__ y, const int* __restrict__ pos_of,
                           const float* __restrict__ topk_w, float* __restrict__ out) {
    int idx = blockIdx.x * 256 + threadIdx.x;    // exactly T * (H/4)
    int t  = idx >> 9;
    int c4 = (idx & 511) << 2;
    int p0 = pos_of[t * 2], p1 = pos_of[t * 2 + 1];
    float w0 = topk_w[t * 2], w1 = topk_w[t * 2 + 1];
    const size_t PS = (size_t)PADMAX * HID;
    f32x4 o = {0.f, 0.f, 0.f, 0.f};
#pragma unroll
    for (int p = 0; p < 4; ++p) {
        u16x4 a = *(const u16x4*)(y + p * PS + (size_t)p0 * HID + c4);
        u16x4 b = *(const u16x4*)(y + p * PS + (size_t)p1 * HID + c4);
#pragma unroll
        for (int q = 0; q < 4; ++q) o[q] += w0 * bf2f(a[q]) + w1 * bf2f(b[q]);
    }
    *(f32x4*)(out + (size_t)t * HID + c4) = o;
    if (idx == 0) out[(size_t)T_TOK * HID] = 0.f;   // second output: zeros((1,))
}

// ---------------- weighted combine (2 partials; fallback path) ----------------
__global__ void k_combine2(const u16* __restrict__ y0, const u16* __restrict__ y1,
                           const int* __restrict__ pos_of,
                           const float* __restrict__ topk_w, float* __restrict__ out) {
    int idx = blockIdx.x * 256 + threadIdx.x;
    int t  = idx >> 9;
    int c4 = (idx & 511) << 2;
    int p0 = pos_of[t * 2], p1 = pos_of[t * 2 + 1];
    float w0 = topk_w[t * 2], w1 = topk_w[t * 2 + 1];
    u16x4 a0 = *(const u16x4*)(y0 + (size_t)p0 * HID + c4);
    u16x4 a1 = *(const u16x4*)(y1 + (size_t)p0 * HID + c4);
    u16x4 b0 = *(const u16x4*)(y0 + (size_t)p1 * HID + c4);
    u16x4 b1 = *(const u16x4*)(y1 + (size_t)p1 * HID + c4);
    f32x4 o;
#pragma unroll
    for (int q = 0; q < 4; ++q)
        o[q] = w0 * (bf2f(a0[q]) + bf2f(a1[q])) + w1 * (bf2f(b0[q]) + bf2f(b1[q]));
    *(f32x4*)(out + (size_t)t * HID + c4) = o;
    if (idx == 0) out[(size_t)T_TOK * HID] = 0.f;
}

__global__ void k_init(int* __restrict__ c) {
    if (threadIdx.x < 16) c[threadIdx.x] = 0;       // counts[8] + cursors[8]
}

extern "C" void kernel_launch(void* const* d_in, const int* in_sizes, int n_in,
                              void* d_out, int out_size, void* d_ws, size_t ws_size,
                              hipStream_t stream) {
    const float* x  = (const float*)d_in[0];
    const float* wr = (const float*)d_in[1];
    const float* w1 = (const float*)d_in[2];
    const float* w2 = (const float*)d_in[3];
    const float* w3 = (const float*)d_in[4];
    float* out = (float*)d_out;
    char* ws = (char*)d_ws;

    const long WN8 = (long)NE * FFN_D * HID / 8;     // per weight tensor, x8 groups
    const size_t NEED = 503459840ull;                // main layout incl. separate w2b

    if (ws_size >= NEED) {
        // ---- main path ----
        u16*  xb  = (u16*)(ws);                          // 16,777,216
        u16*  wA  = (u16*)(ws + 16777216);               // 134,217,728 (w1b)
        u16*  w3b = (u16*)(ws + 150994944);              // 134,217,728 (w3b)
        u16*  hb  = (u16*)(ws + 285212672);              // 83,886,080  (10240 x 4096 bf16)
        u16*  w2b = (u16*)(ws + 369098752);              // 134,217,728
        u16*  yb  = (u16*)(ws + 16777216);               // 4 x 41,943,040 partials (alias w1b+w3b)
        int*  perm_tok = (int*)(ws + 503316480);         // 10240 ints
        int*  pos_of   = (int*)(ws + 503357440);
        int*  topk_id  = (int*)(ws + 503390208);
        float* topk_w  = (float*)(ws + 503422976);
        int*  cnt      = (int*)(ws + 503455744);
        int*  counts   = cnt;
        int*  cursors  = cnt + 8;
        int*  pad_off  = cnt + 16;

        k_init<<<1, 64, 0, stream>>>(cnt);

        // fused: router (blocks 0-1023) + w1/w3 fp32->bf16 convert (blocks 1024+)
        k_pre<<<9216, 256, 0, stream>>>(x, wr, xb, topk_id, topk_w, counts,
                                        w1, wA, w3, w3b, WN8);
        k_scan<<<1, 256, 0, stream>>>(counts, pad_off, perm_tok);
        k_scatter<<<16, 256, 0, stream>>>(topk_id, cursors, pad_off, perm_tok, pos_of);

        // stage 1: h = silu(x@w1^T)*(x@w3^T), dual-B BN=128;
        // + 512 tail blocks convert w2 -> w2b (fills grid-tail idle CUs)
        k_gemm8<HID, FFN_D, 128, 1, true, true, true>
            <<<(FFN_D / 128) * 40 + 512, 512, 0, stream>>>(
            xb, wA, w3b, hb, perm_tok, pad_off, w2, w2b, (FFN_D / 128) * 40, 512);

        // stage 2: y = h @ w2b^T; single-B BN=256, split-K x4 (bf16 partials
        // into the freed w1b/w3b region) -> ~37us blocks pack the grid tail
        k_gemm8<FFN_D, HID, 256, 4, false, false, false>
            <<<(HID / 256) * 40 * 4, 512, 0, stream>>>(
            hb, w2b, (const u16*)nullptr, yb, perm_tok, pad_off,
            (const float*)nullptr, (u16*)nullptr, 0, 0);

        k_combine4<<<8192, 256, 0, stream>>>(yb, pos_of, topk_w, out);
    } else {
        // ---- fallback: R10 sequence (~369.3 MB), split-K x2 ----
        u16*  xb  = (u16*)(ws);                          // 16,777,216
        u16*  wA  = (u16*)(ws + 16777216);               // 134,217,728 (w1b, later w2b)
        u16*  w3b = (u16*)(ws + 150994944);              // 134,217,728
        u16*  hb  = (u16*)(ws + 285212672);              // 83,886,080
        u16*  yb  = (u16*)(ws + 150994944);              // 2 partials alias w3b
        int*  perm_tok = (int*)(ws + 369098752);
        int*  pos_of   = (int*)(ws + 369139712);
        int*  topk_id  = (int*)(ws + 369172480);
        float* topk_w  = (float*)(ws + 369205248);
        int*  cnt      = (int*)(ws + 369238016);
        int*  counts   = cnt;
        int*  cursors  = cnt + 8;
        int*  pad_off  = cnt + 16;

        k_init<<<1, 64, 0, stream>>>(cnt);
        k_router<<<1024, 256, 0, stream>>>(x, wr, xb, topk_id, topk_w, counts);
        k_scan<<<1, 256, 0, stream>>>(counts, pad_off, perm_tok);
        k_scatter<<<16, 256, 0, stream>>>(topk_id, cursors, pad_off, perm_tok, pos_of);

        k_convert2<<<8192, 256, 0, stream>>>(w1, wA, w3, w3b, WN8);

        k_gemm8<HID, FFN_D, 128, 1, true, true, false>
            <<<(FFN_D / 128) * 40, 512, 0, stream>>>(
            xb, wA, w3b, hb, perm_tok, pad_off,
            (const float*)nullptr, (u16*)nullptr, 0, 0);

        k_convert<<<4096, 256, 0, stream>>>(w2, wA, WN8);  // reuse w1's slot

        k_gemm8<FFN_D, HID, 256, 2, false, false, false>
            <<<(HID / 256) * 40 * 2, 512, 0, stream>>>(
            hb, wA, (const u16*)nullptr, yb, perm_tok, pad_off,
            (const float*)nullptr, (u16*)nullptr, 0, 0);

        k_combine2<<<8192, 256, 0, stream>>>(yb, yb + (size_t)PADMAX * HID,
                                             pos_of, topk_w, out);
    }
}